// Round 4
// baseline (1126.830 us; speedup 1.0000x reference)
//
#include <hip/hip_runtime.h>
#include <stdint.h>

// f32 forward of bin_weight exactly as the reference computes it:
// q = 0.1f*sign(w); return w + (q - w), each op IEEE f32.
__device__ __forceinline__ float dance(float w) {
  float q = w > 0.f ? 0.1f : (w < 0.f ? -0.1f : 0.0f);
  float r = __fsub_rn(q, w);
  return __fadd_rn(w, r);
}

__device__ __forceinline__ int sgn(float u) {
  return u > 0.f ? 1 : (u < 0.f ? -1 : 0);
}

// pack: w[oc][ic][kw] -> wt[k][oc], k = ic*KW+kw, with the f32 dance applied.
__global__ void pack_dance(const float* __restrict__ w, float* __restrict__ out,
                           int OC, int ICKW) {
  int idx = blockIdx.x * 256 + threadIdx.x;
  if (idx >= OC * ICKW) return;
  int oc = idx / ICKW, k = idx - oc * ICKW;
  out[(size_t)k * OC + oc] = dance(w[idx]);
}

// conv1: x(128,1,16000), w1t[k][oc], stride 4, VALID -> 3981; +b1; bn; sign; pool4.
// Sequential k=0..79 FMA chain per output element (BLAS semantics).
__global__ __launch_bounds__(128) void conv1_np(
    const float* __restrict__ x, const float* __restrict__ w1t,
    const float* __restrict__ b1, const float* __restrict__ s1,
    const float* __restrict__ o1, int8_t* __restrict__ a1) {
  __shared__ float xs[92];
  const int tp = blockIdx.x;   // 0..994
  const int b = blockIdx.y;
  const int oc = threadIdx.x;  // 0..127
  const float* xp = x + (size_t)b * 16000 + 16 * tp;  // max 16*994+91 = 15995
  for (int i = oc; i < 92; i += 128) xs[i] = xp[i];
  __syncthreads();
  float z0 = 0.f, z1 = 0.f, z2 = 0.f, z3 = 0.f;
  for (int k = 0; k < 80; ++k) {
    float w = w1t[k * 128 + oc];
    z0 = __builtin_fmaf(w, xs[k], z0);
    z1 = __builtin_fmaf(w, xs[4 + k], z1);
    z2 = __builtin_fmaf(w, xs[8 + k], z2);
    z3 = __builtin_fmaf(w, xs[12 + k], z3);
  }
  const float bv = b1[oc], sv = s1[oc], ov = o1[oc];
  float zz[4] = {z0, z1, z2, z3};
  int m = -2;
#pragma unroll
  for (int g = 0; g < 4; ++g) {
    float y = __fadd_rn(zz[g], bv);
    float t = __fmul_rn(y, sv);
    float u = __fadd_rn(t, ov);
    m = max(m, sgn(u));
  }
  a1[((size_t)b * 995 + tp) * 128 + oc] = (int8_t)m;
}

// convN (KW=3): a_in[b][Tin][CIN] i8; wt[k][COUT], k=i*3+h; +bias; bn; sign; pool4.
// Each output element: one sequential f32 FMA chain over k ascending.
template <int CIN>
__global__ void convN_np(const int8_t* __restrict__ ain,
                         const float* __restrict__ wt,
                         const float* __restrict__ bias,
                         const float* __restrict__ bns,
                         const float* __restrict__ bno,
                         int8_t* __restrict__ aout,
                         int Tin, int TPout, int COUT) {
  extern __shared__ float as_[];  // [6][CIN] f32 (rows 4tp..4tp+5)
  const int tp = blockIdx.x;
  const int b = blockIdx.y;
  const int oc = threadIdx.x;     // blockDim.x == COUT
  const int8_t* src = ain + ((size_t)b * Tin + 4 * tp) * CIN;
  for (int i = oc; i < 6 * CIN; i += COUT) as_[i] = (float)src[i];
  __syncthreads();
  float z[4] = {0.f, 0.f, 0.f, 0.f};
  for (int i = 0; i < CIN; ++i) {
#pragma unroll
    for (int h = 0; h < 3; ++h) {
      float w = wt[(size_t)(i * 3 + h) * COUT + oc];
#pragma unroll
      for (int g = 0; g < 4; ++g)
        z[g] = __builtin_fmaf(w, as_[(g + h) * CIN + i], z[g]);
    }
  }
  const float bv = bias[oc], sv = bns[oc], ov = bno[oc];
  int m = -2;
#pragma unroll
  for (int g = 0; g < 4; ++g) {
    float y = __fadd_rn(z[g], bv);
    float t = __fmul_rn(y, sv);
    float u = __fadd_rn(t, ov);
    m = max(m, sgn(u));
  }
  aout[((size_t)b * TPout + tp) * COUT + oc] = (int8_t)m;
}

// emb: a4[b][14][512] i8, wEt[k][512] (k=i*14+h), single position; +bemb -> yemb f32.
// 8 b per block for weight reuse; sequential k FMA chain per output.
__global__ __launch_bounds__(256) void emb_np(
    const int8_t* __restrict__ a4, const float* __restrict__ wEt,
    const float* __restrict__ bemb, float* __restrict__ yemb) {
  __shared__ int8_t a4s[8 * 7168];  // 57344 B
  const int ocg = blockIdx.x;   // 0..7
  const int bg = blockIdx.y;    // 0..15
  const int tid = threadIdx.x;  // 0..255
  const int8_t* src = a4 + (size_t)bg * 8 * 7168;
  for (int i = tid; i < 8 * 7168; i += 256) a4s[i] = src[i];
  __syncthreads();
  const int oc = ocg * 64 + (tid & 63);
  const int bs = tid >> 6;  // 0..3 -> pair of b
  const int8_t* pa = a4s + (size_t)(bs * 2) * 7168;
  const int8_t* pb = pa + 7168;
  float za = 0.f, zb = 0.f;
  for (int i = 0; i < 512; ++i) {
#pragma unroll
    for (int h = 0; h < 14; ++h) {
      float w = wEt[(size_t)(i * 14 + h) * 512 + oc];
      za = __builtin_fmaf(w, (float)pa[h * 512 + i], za);
      zb = __builtin_fmaf(w, (float)pb[h * 512 + i], zb);
    }
  }
  const float be = bemb[oc];
  const int b0 = bg * 8 + bs * 2;
  yemb[(size_t)b0 * 512 + oc] = __fadd_rn(za, be);
  yemb[(size_t)(b0 + 1) * 512 + oc] = __fadd_rn(zb, be);
}

// fc1 (seq FMA) + bn + sign + fc2 (seq FMA) -> out f32
__global__ __launch_bounds__(256) void fc_np(
    const float* __restrict__ yemb, const float* __restrict__ w1t,
    const float* __restrict__ s1, const float* __restrict__ o1,
    const float* __restrict__ w2t, float* __restrict__ out) {
  __shared__ float ys[512];
  __shared__ float a5[256];
  const int b = blockIdx.x;
  const int tid = threadIdx.x;
  for (int i = tid; i < 512; i += 256) ys[i] = yemb[(size_t)b * 512 + i];
  __syncthreads();
  float z = 0.f;
  for (int k = 0; k < 512; ++k)
    z = __builtin_fmaf(w1t[k * 256 + tid], ys[k], z);
  float t = __fmul_rn(z, s1[tid]);
  float u = __fadd_rn(t, o1[tid]);
  a5[tid] = u > 0.f ? 1.f : (u < 0.f ? -1.f : 0.f);
  __syncthreads();
  if (tid < 35) {
    float z2 = 0.f;
    for (int k = 0; k < 256; ++k)
      z2 = __builtin_fmaf(w2t[k * 35 + tid], a5[k], z2);
    out[(size_t)b * 35 + tid] = z2;
  }
}

extern "C" void kernel_launch(void* const* d_in, const int* in_sizes, int n_in,
                              void* d_out, int out_size, void* d_ws, size_t ws_size,
                              hipStream_t stream) {
  const float* x    = (const float*)d_in[0];
  const float* w1   = (const float*)d_in[1];
  const float* b1   = (const float*)d_in[2];
  const float* bn1s = (const float*)d_in[3];
  const float* bn1b = (const float*)d_in[4];
  const float* w2   = (const float*)d_in[5];
  const float* b2   = (const float*)d_in[6];
  const float* bn2s = (const float*)d_in[7];
  const float* bn2b = (const float*)d_in[8];
  const float* w3   = (const float*)d_in[9];
  const float* b3   = (const float*)d_in[10];
  const float* bn3s = (const float*)d_in[11];
  const float* bn3b = (const float*)d_in[12];
  const float* w5   = (const float*)d_in[13];
  const float* b5   = (const float*)d_in[14];
  const float* bn5s = (const float*)d_in[15];
  const float* bn5b = (const float*)d_in[16];
  const float* wemb = (const float*)d_in[17];
  const float* bemb = (const float*)d_in[18];
  const float* wfc1 = (const float*)d_in[19];
  const float* fc1s = (const float*)d_in[20];
  const float* fc1b = (const float*)d_in[21];
  const float* wfc2 = (const float*)d_in[22];
  float* out = (float*)d_out;

  uint8_t* ws = (uint8_t*)d_ws;
  size_t off = 0;
  auto carve = [&](size_t bytes) {
    void* p = ws + off;
    off = (off + bytes + 255) & ~(size_t)255;
    return p;
  };
  int8_t* a1   = (int8_t*)carve((size_t)128 * 995 * 128);
  int8_t* a2   = (int8_t*)carve((size_t)128 * 248 * 128);
  int8_t* a3   = (int8_t*)carve((size_t)128 * 61 * 256);
  int8_t* a4   = (int8_t*)carve((size_t)128 * 14 * 512);
  float* yemb  = (float*)carve((size_t)128 * 512 * 4);
  float* w1t   = (float*)carve((size_t)80 * 128 * 4);
  float* w2t   = (float*)carve((size_t)384 * 128 * 4);
  float* w3t   = (float*)carve((size_t)384 * 256 * 4);
  float* w5t   = (float*)carve((size_t)768 * 512 * 4);
  float* wEt   = (float*)carve((size_t)7168 * 512 * 4);
  float* fc1t  = (float*)carve((size_t)512 * 256 * 4);
  float* fc2t  = (float*)carve((size_t)256 * 35 * 4);

  auto packs = [&](const float* w, float* o, int OC, int ICKW) {
    pack_dance<<<dim3((OC * ICKW + 255) / 256), 256, 0, stream>>>(w, o, OC, ICKW);
  };
  packs(w1, w1t, 128, 80);
  packs(w2, w2t, 128, 384);
  packs(w3, w3t, 256, 384);
  packs(w5, w5t, 512, 768);
  packs(wemb, wEt, 512, 7168);
  packs(wfc1, fc1t, 256, 512);
  packs(wfc2, fc2t, 35, 256);

  conv1_np<<<dim3(995, 128), 128, 0, stream>>>(x, w1t, b1, bn1s, bn1b, a1);

  convN_np<128><<<dim3(248, 128), 128, 6 * 128 * 4, stream>>>(
      a1, w2t, b2, bn2s, bn2b, a2, 995, 248, 128);
  convN_np<128><<<dim3(61, 128), 256, 6 * 128 * 4, stream>>>(
      a2, w3t, b3, bn3s, bn3b, a3, 248, 61, 256);
  convN_np<256><<<dim3(14, 128), 512, 6 * 256 * 4, stream>>>(
      a3, w5t, b5, bn5s, bn5b, a4, 61, 14, 512);

  emb_np<<<dim3(8, 16), 256, 0, stream>>>(a4, wEt, bemb, yemb);

  fc_np<<<dim3(128), 256, 0, stream>>>(yemb, fc1t, fc1s, fc1b, fc2t, out);
}

// Round 5
// 896.373 us; speedup vs baseline: 1.2571x; 1.2571x over previous
//
#include <hip/hip_runtime.h>
#include <stdint.h>

// f32 forward of bin_weight exactly as the reference computes it:
// q = 0.1f*sign(w); return w + (q - w), each op IEEE f32.
__device__ __forceinline__ float dance(float w) {
  float q = w > 0.f ? 0.1f : (w < 0.f ? -0.1f : 0.0f);
  float r = __fsub_rn(q, w);
  return __fadd_rn(w, r);
}

__device__ __forceinline__ int sgn(float u) {
  return u > 0.f ? 1 : (u < 0.f ? -1 : 0);
}

// pack: w[oc][ic][kw] -> wt[k][oc], k = ic*KW+kw, with the f32 dance applied.
__global__ void pack_dance(const float* __restrict__ w, float* __restrict__ out,
                           int OC, int ICKW) {
  int idx = blockIdx.x * 256 + threadIdx.x;
  if (idx >= OC * ICKW) return;
  int oc = idx / ICKW, k = idx - oc * ICKW;
  out[(size_t)k * OC + oc] = dance(w[idx]);
}

// ---------------- conv1: weights in registers, rolling float4 window ----------------
// x(128,1,16000) stride4 VALID -> 3981 pos; +b1; bn; sign; pool4 -> a1[b][995][128] i8
// Chain (b,tp,g,oc): z = seq FMA k=0..79 (identical order to round-4 PASS).
// NTP=2 pooled positions, NB=2 batches per block; 16 chains/thread.
__global__ __launch_bounds__(128) void conv1_fast(
    const float* __restrict__ x, const float* __restrict__ w1t,
    const float* __restrict__ b1, const float* __restrict__ s1,
    const float* __restrict__ o1, int8_t* __restrict__ a1) {
  __shared__ float xs[2][112];               // per-b window: 2*16+76 = 108 floats
  const int tid = threadIdx.x;               // oc
  const int tp0 = blockIdx.x * 2;            // 498 groups (995 -> clamp tail)
  const int b0 = blockIdx.y * 2;
  for (int t = tid; t < 2 * 108; t += 128) {
    int nb = t / 108, j = t - nb * 108;
    xs[nb][j] = x[(size_t)(b0 + nb) * 16000 + min(16 * tp0 + j, 15999)];
  }
  // one-time coalesced weight preload -> 80 registers (constant-indexed)
  float wreg[80];
#pragma unroll
  for (int k = 0; k < 80; ++k) wreg[k] = w1t[k * 128 + tid];
  __syncthreads();

  const int sb0 = 4 * (min(tp0 + 0, 994) - tp0);   // float4-slot base per p (0 / 4)
  const int sb1 = 4 * (min(tp0 + 1, 994) - tp0);
  float z[2][2][4] = {};                     // [nb][p][g]
  const float4* x40 = (const float4*)xs[0];
  const float4* x41 = (const float4*)xs[1];
#pragma unroll
  for (int q = 0; q < 20; ++q) {             // k = 4q + ii
#pragma unroll
    for (int nb = 0; nb < 2; ++nb) {
      const float4* x4 = nb ? x41 : x40;
#pragma unroll
      for (int p = 0; p < 2; ++p) {
        const int sb = p ? sb1 : sb0;
        float4 v0 = x4[sb + q + 0];
        float4 v1 = x4[sb + q + 1];
        float4 v2 = x4[sb + q + 2];
        float4 v3 = x4[sb + q + 3];
        float4 vv[4] = {v0, v1, v2, v3};
#pragma unroll
        for (int g = 0; g < 4; ++g) {
          float zz = z[nb][p][g];
          zz = __builtin_fmaf(wreg[4 * q + 0], vv[g].x, zz);
          zz = __builtin_fmaf(wreg[4 * q + 1], vv[g].y, zz);
          zz = __builtin_fmaf(wreg[4 * q + 2], vv[g].z, zz);
          zz = __builtin_fmaf(wreg[4 * q + 3], vv[g].w, zz);
          z[nb][p][g] = zz;
        }
      }
    }
  }
  const float bv = b1[tid], sv = s1[tid], ov = o1[tid];
#pragma unroll
  for (int nb = 0; nb < 2; ++nb)
#pragma unroll
    for (int p = 0; p < 2; ++p) {
      int m = -2;
#pragma unroll
      for (int g = 0; g < 4; ++g) {
        float y = __fadd_rn(z[nb][p][g], bv);
        float t2 = __fmul_rn(y, sv);
        float u = __fadd_rn(t2, ov);
        m = max(m, sgn(u));
      }
      int tpc = min(tp0 + p, 994);
      a1[((size_t)(b0 + nb) * 995 + tpc) * 128 + tid] = (int8_t)m;
    }
}

// ---------------- convN (KW=3): register-blocked, b128 LDS window ----------------
// Chain (b,tp,g,oc): z = seq FMA over k = i*3+h ascending (ii outer, h inner).
template <int CIN, int COUT, int NTP, int NB>
__global__ __launch_bounds__(COUT) void convN_fast(
    const int8_t* __restrict__ ain, const float* __restrict__ wt,
    const float* __restrict__ bias, const float* __restrict__ bns,
    const float* __restrict__ bno, int8_t* __restrict__ aout,
    int Tin, int TPout) {
  constexpr int ROWS = 4 * NTP + 2;
  __shared__ float as_[NB][ROWS][CIN];
  const int tid = threadIdx.x;               // oc
  const int tp0 = blockIdx.x * NTP;
  const int b0 = blockIdx.y * NB;
  for (int t = tid; t < NB * ROWS * CIN; t += COUT) {
    int nb = t / (ROWS * CIN);
    int rem = t - nb * (ROWS * CIN);
    int r = rem / CIN;
    int c = rem - r * CIN;
    int gr = min(4 * tp0 + r, Tin - 1);
    as_[nb][r][c] = (float)ain[((size_t)(b0 + nb) * Tin + gr) * CIN + c];
  }
  __syncthreads();

  int rb[NTP];
#pragma unroll
  for (int p = 0; p < NTP; ++p) rb[p] = 4 * min(tp0 + p, TPout - 1) - 4 * tp0;

  float z[NB][NTP][4] = {};
  for (int i = 0; i < CIN; i += 4) {
    float w[4][3];
#pragma unroll
    for (int ii = 0; ii < 4; ++ii)
#pragma unroll
      for (int h = 0; h < 3; ++h)
        w[ii][h] = wt[(size_t)((i + ii) * 3 + h) * COUT + tid];
#pragma unroll
    for (int nb = 0; nb < NB; ++nb) {
#pragma unroll
      for (int p = 0; p < NTP; ++p) {
        float r4[6][4];
#pragma unroll
        for (int r = 0; r < 6; ++r)
          *(float4*)r4[r] = *(const float4*)&as_[nb][rb[p] + r][i];
#pragma unroll
        for (int g = 0; g < 4; ++g) {
          float zz = z[nb][p][g];
#pragma unroll
          for (int ii = 0; ii < 4; ++ii) {
            zz = __builtin_fmaf(w[ii][0], r4[g + 0][ii], zz);
            zz = __builtin_fmaf(w[ii][1], r4[g + 1][ii], zz);
            zz = __builtin_fmaf(w[ii][2], r4[g + 2][ii], zz);
          }
          z[nb][p][g] = zz;
        }
      }
    }
  }
  const float bv = bias[tid], sv = bns[tid], ov = bno[tid];
#pragma unroll
  for (int nb = 0; nb < NB; ++nb)
#pragma unroll
    for (int p = 0; p < NTP; ++p) {
      int m = -2;
#pragma unroll
      for (int g = 0; g < 4; ++g) {
        float y = __fadd_rn(z[nb][p][g], bv);
        float t2 = __fmul_rn(y, sv);
        float u = __fadd_rn(t2, ov);
        m = max(m, sgn(u));
      }
      int tpc = min(tp0 + p, TPout - 1);
      aout[((size_t)(b0 + nb) * TPout + tpc) * COUT + tid] = (int8_t)m;
    }
}

// ---------------- emb: a4[b][14][512] i8, wEt[k][512] (k=i*14+h) ----------------
__global__ __launch_bounds__(256) void emb_np(
    const int8_t* __restrict__ a4, const float* __restrict__ wEt,
    const float* __restrict__ bemb, float* __restrict__ yemb) {
  __shared__ int8_t a4s[8 * 7168];
  const int ocg = blockIdx.x;   // 0..7
  const int bg = blockIdx.y;    // 0..15
  const int tid = threadIdx.x;  // 0..255
  const int8_t* src = a4 + (size_t)bg * 8 * 7168;
  for (int i = tid; i < 8 * 7168; i += 256) a4s[i] = src[i];
  __syncthreads();
  const int oc = ocg * 64 + (tid & 63);
  const int bs = tid >> 6;
  const int8_t* pa = a4s + (size_t)(bs * 2) * 7168;
  const int8_t* pb = pa + 7168;
  float za = 0.f, zb = 0.f;
  for (int i = 0; i < 512; ++i) {
#pragma unroll
    for (int h = 0; h < 14; ++h) {
      float w = wEt[(size_t)(i * 14 + h) * 512 + oc];
      za = __builtin_fmaf(w, (float)pa[h * 512 + i], za);
      zb = __builtin_fmaf(w, (float)pb[h * 512 + i], zb);
    }
  }
  const float be = bemb[oc];
  const int b0 = bg * 8 + bs * 2;
  yemb[(size_t)b0 * 512 + oc] = __fadd_rn(za, be);
  yemb[(size_t)(b0 + 1) * 512 + oc] = __fadd_rn(zb, be);
}

// ---------------- fc1 + bn + sign + fc2 ----------------
__global__ __launch_bounds__(256) void fc_np(
    const float* __restrict__ yemb, const float* __restrict__ w1t,
    const float* __restrict__ s1, const float* __restrict__ o1,
    const float* __restrict__ w2t, float* __restrict__ out) {
  __shared__ float ys[512];
  __shared__ float a5[256];
  const int b = blockIdx.x;
  const int tid = threadIdx.x;
  for (int i = tid; i < 512; i += 256) ys[i] = yemb[(size_t)b * 512 + i];
  __syncthreads();
  float z = 0.f;
  for (int k = 0; k < 512; ++k)
    z = __builtin_fmaf(w1t[k * 256 + tid], ys[k], z);
  float t = __fmul_rn(z, s1[tid]);
  float u = __fadd_rn(t, o1[tid]);
  a5[tid] = u > 0.f ? 1.f : (u < 0.f ? -1.f : 0.f);
  __syncthreads();
  if (tid < 35) {
    float z2 = 0.f;
    for (int k = 0; k < 256; ++k)
      z2 = __builtin_fmaf(w2t[k * 35 + tid], a5[k], z2);
    out[(size_t)b * 35 + tid] = z2;
  }
}

extern "C" void kernel_launch(void* const* d_in, const int* in_sizes, int n_in,
                              void* d_out, int out_size, void* d_ws, size_t ws_size,
                              hipStream_t stream) {
  const float* x    = (const float*)d_in[0];
  const float* w1   = (const float*)d_in[1];
  const float* b1   = (const float*)d_in[2];
  const float* bn1s = (const float*)d_in[3];
  const float* bn1b = (const float*)d_in[4];
  const float* w2   = (const float*)d_in[5];
  const float* b2   = (const float*)d_in[6];
  const float* bn2s = (const float*)d_in[7];
  const float* bn2b = (const float*)d_in[8];
  const float* w3   = (const float*)d_in[9];
  const float* b3   = (const float*)d_in[10];
  const float* bn3s = (const float*)d_in[11];
  const float* bn3b = (const float*)d_in[12];
  const float* w5   = (const float*)d_in[13];
  const float* b5   = (const float*)d_in[14];
  const float* bn5s = (const float*)d_in[15];
  const float* bn5b = (const float*)d_in[16];
  const float* wemb = (const float*)d_in[17];
  const float* bemb = (const float*)d_in[18];
  const float* wfc1 = (const float*)d_in[19];
  const float* fc1s = (const float*)d_in[20];
  const float* fc1b = (const float*)d_in[21];
  const float* wfc2 = (const float*)d_in[22];
  float* out = (float*)d_out;

  uint8_t* ws = (uint8_t*)d_ws;
  size_t off = 0;
  auto carve = [&](size_t bytes) {
    void* p = ws + off;
    off = (off + bytes + 255) & ~(size_t)255;
    return p;
  };
  int8_t* a1   = (int8_t*)carve((size_t)128 * 995 * 128);
  int8_t* a2   = (int8_t*)carve((size_t)128 * 248 * 128);
  int8_t* a3   = (int8_t*)carve((size_t)128 * 61 * 256);
  int8_t* a4   = (int8_t*)carve((size_t)128 * 14 * 512);
  float* yemb  = (float*)carve((size_t)128 * 512 * 4);
  float* w1t   = (float*)carve((size_t)80 * 128 * 4);
  float* w2t   = (float*)carve((size_t)384 * 128 * 4);
  float* w3t   = (float*)carve((size_t)384 * 256 * 4);
  float* w5t   = (float*)carve((size_t)768 * 512 * 4);
  float* wEt   = (float*)carve((size_t)7168 * 512 * 4);
  float* fc1t  = (float*)carve((size_t)512 * 256 * 4);
  float* fc2t  = (float*)carve((size_t)256 * 35 * 4);

  auto packs = [&](const float* w, float* o, int OC, int ICKW) {
    pack_dance<<<dim3((OC * ICKW + 255) / 256), 256, 0, stream>>>(w, o, OC, ICKW);
  };
  packs(w1, w1t, 128, 80);
  packs(w2, w2t, 128, 384);
  packs(w3, w3t, 256, 384);
  packs(w5, w5t, 512, 768);
  packs(wemb, wEt, 512, 7168);
  packs(wfc1, fc1t, 256, 512);
  packs(wfc2, fc2t, 35, 256);

  // conv1: 498 tp-groups (NTP=2, clamp tail) x 64 batch-pairs
  conv1_fast<<<dim3(498, 64), 128, 0, stream>>>(x, w1t, b1, bn1s, bn1b, a1);

  // conv2: Tin=995 TPout=248; NTP=4 NB=2 -> grid(62,64), 128 thr
  convN_fast<128, 128, 4, 2><<<dim3(62, 64), 128, 0, stream>>>(
      a1, w2t, b2, bn2s, bn2b, a2, 995, 248);
  // conv3: Tin=248 TPout=61; NTP=4 NB=2 -> grid(16,64), 256 thr
  convN_fast<128, 256, 4, 2><<<dim3(16, 64), 256, 0, stream>>>(
      a2, w3t, b3, bn3s, bn3b, a3, 248, 61);
  // conv5: Tin=61 TPout=14; NTP=2 NB=2 -> grid(7,64), 512 thr
  convN_fast<256, 512, 2, 2><<<dim3(7, 64), 512, 0, stream>>>(
      a3, w5t, b5, bn5s, bn5b, a4, 61, 14);

  emb_np<<<dim3(8, 16), 256, 0, stream>>>(a4, wEt, bemb, yemb);

  fc_np<<<dim3(128), 256, 0, stream>>>(yemb, fc1t, fc1s, fc1b, fc2t, out);
}